// Round 19
// baseline (62.852 us; speedup 1.0000x reference)
//
#include <hip/hip_runtime.h>

#define NGT 30000
#define GT_TILE 512
#define NBLK_G 59            // ceil(30000/512)
#define PRANGE 128           // preds per block
#define NCHUNK 27            // m0: 2, m1: 5, m2: 20 chunks of 128
#define NPACK 3456           // 27 * 128 chunk-padded pred slots
#define RB 128               // reduce blocks

typedef float v2f __attribute__((ext_vector_type(2)));

// ws layout (float offsets). predpack first (16B aligned at ws base).
#define OFF_PREDPACK 0              // 3456 float4 = 13824 floats
#define OFF_GTMIN    13824          // 3*30000 = 90000 (16B-aligned)
#define OFF_PREDMIN  103824         // 3240
#define OFF_PARTIALS 107064         // RB*4 = 512
#define OFF_COUNTER  107576         // 1 uint

__device__ __forceinline__ float rdlane(float v, int k) {
    return __int_as_float(__builtin_amdgcn_readlane(__float_as_int(v), k));
}

// ---------------------------------------------------------------------------
// Pack kernel: predpack[i] = {x,y,z,norm} (sentinel w=3e38 for pad slots);
// inits gtmin[90000] + predmin[3240] and zeroes the done-counter.
// predpack: m0 [0,256), m1 [256,896), m2 [896,3456).
// ---------------------------------------------------------------------------
__global__ __launch_bounds__(256) void pack_kernel(
    const float* __restrict__ pbd0,
    const float* __restrict__ pbd1,
    const float* __restrict__ pbd2,
    float4* __restrict__ predpack,
    float* __restrict__ gtmin,
    float* __restrict__ predmin,
    unsigned* __restrict__ counter)
{
    const int i = blockIdx.x * 256 + threadIdx.x;
    if (i == 0) *counter = 0u;
    if (i < 90000) gtmin[i] = __int_as_float(0x7f7f7f7f);
    else if (i < 93240) predmin[i - 90000] = __int_as_float(0x7f7f7f7f);
    if (i >= NPACK) return;
    int mesh, j, n;
    if (i < 256)      { mesh = 0; j = i;       n = 156; }
    else if (i < 896) { mesh = 1; j = i - 256; n = 618; }
    else              { mesh = 2; j = i - 896; n = 2466; }
    const float* p = (mesh == 0) ? pbd0 : (mesh == 1) ? pbd1 : pbd2;
    float4 v = make_float4(0.f, 0.f, 0.f, 3.0e38f);
    if (j < n) {
        float x = p[3*j], y = p[3*j+1], z = p[3*j+2];
        v = make_float4(x, y, z, x*x + y*y + z*z);
    }
    predpack[i] = v;
}

// ---------------------------------------------------------------------------
// ZERO-LDS two-phase chamfer via register-broadcast (R19).
// R18 post-mortem: 896 DS ops/block (512 sgt staging writes + 128 spred +
// 256 phase-2 reads) x ~12cyc x 6.2 blocks/CU ~= 28us/CU — the measured
// chamfer floor. This version has NO LDS and NO barriers.
// grid = (59, 27) = 1593 blocks, block = 256.
// Phase 1: 2 gt/thread in regs; 128 preds via wave-uniform s_load_dwordx4
//          from predpack (2 KB slice, K$-shared by same-y blocks); packed
//          v_pk_fma (~3 VALU/pair); atomicMin gtmin[m][g].
// Phase 2: wave's 128 gt points live in its lanes' registers; broadcast
//          each via v_readlane (VALU, wave-uniform SGPR lane index = loop
//          counter); each lane owns 2 preds (coalesced predpack loads) and
//          accumulates a complete min -> direct atomicMin predmin.
// atomicMin on int bits of non-negative floats: exact, order-independent,
// deterministic; init 0x7f7f7f7f. Sentinels (pred w=3e38, gt coords 1e18)
// never win a min.
// ---------------------------------------------------------------------------
__global__ __launch_bounds__(256) void chamfer_kernel(
    const float* __restrict__ gt,
    const float4* __restrict__ predpack,
    float* __restrict__ gtmin,     // [3*NGT], pre-init by pack_kernel
    float* __restrict__ predmin)   // [3240],  pre-init by pack_kernel
{
    const int tid = threadIdx.x;
    const int lane = tid & 63;
    const int c = blockIdx.y;

    int mesh, cidx;
    if (c < 2)      { mesh = 0; cidx = c; }
    else if (c < 7) { mesh = 1; cidx = c - 2; }
    else            { mesh = 2; cidx = c - 7; }
    const int coff = cidx * PRANGE;
    const int n    = (mesh == 0) ? 156 : (mesh == 1) ? 618 : 2466;
    const int poff = (mesh == 0) ? 0   : (mesh == 1) ? 156 : 774;
    const int pbase = ((mesh == 0) ? 0 : (mesh == 1) ? 256 : 896) + coff;
    const int np = min(PRANGE, n - coff);

    const int gbase = blockIdx.x * GT_TILE;
    float gx[2], gy[2], gz[2], g2[2];
    #pragma unroll
    for (int k = 0; k < 2; ++k) {
        const int g = gbase + k * 256 + tid;
        float x = 1e18f, y = 1e18f, z = 1e18f;   // sentinel gt: huge, finite
        if (g < NGT) { x = gt[3*g]; y = gt[3*g+1]; z = gt[3*g+2]; }
        gx[k] = x; gy[k] = y; gz[k] = z;
        g2[k] = x*x + y*y + z*z;
    }

    // ---- phase 1: gt-side min; uniform s_load preds + packed f32 math ----
    {
        v2f gxv = {gx[0], gx[1]};
        v2f gyv = {gy[0], gy[1]};
        v2f gzv = {gz[0], gz[1]};
        v2f gminv = {3.0e38f, 3.0e38f};
        const float4* __restrict__ pp = predpack + pbase;  // uniform base
        #pragma unroll 8
        for (int j = 0; j < PRANGE; ++j) {
            const float4 p = pp[j];              // uniform -> s_load_dwordx4
            v2f dot = gxv * p.x;
            dot += gyv * p.y;                    // v_pk_fma
            dot += gzv * p.z;
            v2f t = dot * -2.0f + p.w;           // p2 - 2*dot (packed fma)
            gminv.x = fminf(gminv.x, t.x);
            gminv.y = fminf(gminv.y, t.y);
        }
        int g = gbase + tid;
        if (g < NGT)
            atomicMin((int*)(gtmin + mesh * NGT + g),
                      __float_as_int(gminv.x + g2[0]));
        g += 256;
        if (g < NGT)
            atomicMin((int*)(gtmin + mesh * NGT + g),
                      __float_as_int(gminv.y + g2[1]));
    }

    // ---- phase 2: pred-side min via v_readlane broadcast (no LDS) ----
    {
        const float4 P0 = predpack[pbase + 2*lane];      // coalesced, L2-hit
        const float4 P1 = predpack[pbase + 2*lane + 1];
        v2f px = {P0.x, P1.x};
        v2f py = {P0.y, P1.y};
        v2f pz = {P0.z, P1.z};
        v2f mn = {3.0e38f, 3.0e38f};
        #pragma unroll 4
        for (int k = 0; k < 64; ++k) {           // k uniform -> SGPR lane idx
            #pragma unroll
            for (int h = 0; h < 2; ++h) {
                const float bx = rdlane(gx[h], k);
                const float by = rdlane(gy[h], k);
                const float bz = rdlane(gz[h], k);
                const float b2 = rdlane(g2[h], k);
                v2f dot = px * bx;
                dot += py * by;                  // v_pk_fma (1 SGPR operand)
                dot += pz * bz;
                v2f t = dot * -2.0f + b2;        // g2 - 2*dot
                mn.x = fminf(mn.x, t.x);
                mn.y = fminf(mn.y, t.y);
            }
        }
        const int pj0 = 2*lane, pj1 = 2*lane + 1;
        if (pj0 < np)
            atomicMin((int*)(predmin + poff + coff + pj0),
                      __float_as_int(mn.x + P0.w));
        if (pj1 < np)
            atomicMin((int*)(predmin + poff + coff + pj1),
                      __float_as_int(mn.y + P1.w));
    }
}

// ---------------------------------------------------------------------------
// Partial reduce + fused final (last-block pattern), unchanged from R18.
// Index space: [0,22500) gtmin float4 | [22500,25740) predmin |
// [25740,35442) edges | [35442,38682) laplace.
// ---------------------------------------------------------------------------
__global__ __launch_bounds__(256) void partial_kernel(
    const float* __restrict__ pc0, const float* __restrict__ pc1, const float* __restrict__ pc2,
    const float* __restrict__ pbd0, const float* __restrict__ pbd1, const float* __restrict__ pbd2,
    const int* __restrict__ ed0, const int* __restrict__ ed1, const int* __restrict__ ed2,
    const int* __restrict__ li0, const int* __restrict__ li1, const int* __restrict__ li2,
    const float* __restrict__ gtmin, const float* __restrict__ predmin,
    float* __restrict__ partials, unsigned* __restrict__ counter,
    float* __restrict__ out)
{
    const int   NVs[3]   = {156, 618, 2466};
    const int   NEs[3]   = {462, 1848, 7392};
    const int   poffs[3] = {0, 156, 774};
    const int   eoffs[3] = {0, 462, 2310};
    const float lapc[3]  = {0.2f, 1.0f, 1.0f};
    const float* pcs[3]  = {pc0, pc1, pc2};
    const float* pbds[3] = {pbd0, pbd1, pbd2};
    const int*   eds[3]  = {ed0, ed1, ed2};
    const int*   lis[3]  = {li0, li1, li2};

    const int tid = threadIdx.x;
    const int stride = gridDim.x * 256;
    float ch = 0.f, ed = 0.f, lp = 0.f;

    for (int idx = blockIdx.x * 256 + tid; idx < 38682; idx += stride) {
        if (idx < 22500) {
            const float4 q = ((const float4*)gtmin)[idx];
            ch += (q.x + q.y + q.z + q.w) * (1.0f / 30000.0f);
        } else if (idx < 25740) {
            int p = idx - 22500;
            int m = (p < 156) ? 0 : (p < 774) ? 1 : 2;
            ch += predmin[p] * (1.0f / (float)NVs[m]);
        } else if (idx < 35442) {
            int e = idx - 25740;
            int m = (e < 462) ? 0 : (e < 2310) ? 1 : 2;
            int el = e - eoffs[m];
            const int* E = eds[m];
            const float* P = pcs[m];
            int a = E[2*el], b = E[2*el+1];
            float dx = P[3*a]   - P[3*b];
            float dy = P[3*a+1] - P[3*b+1];
            float dz = P[3*a+2] - P[3*b+2];
            ed += (dx*dx + dy*dy + dz*dz) * (300.0f / (float)NEs[m]);
        } else {
            int v = idx - 35442;
            int m = (v < 156) ? 0 : (v < 774) ? 1 : 2;
            int vl = v - poffs[m];
            const int* L = lis[m];
            const float* PB = pbds[m];
            const float* PC = pcs[m];
            float mvx = PB[3*vl]   - PC[3*vl];
            float mvy = PB[3*vl+1] - PC[3*vl+1];
            float mvz = PB[3*vl+2] - PC[3*vl+2];
            float sx = 0.f, sy = 0.f, sz = 0.f;
            #pragma unroll
            for (int k = 0; k < 8; ++k) {
                int nb = L[10*vl + k];
                if (nb >= 0) {
                    sx += PB[3*nb]   - PC[3*nb];
                    sy += PB[3*nb+1] - PC[3*nb+1];
                    sz += PB[3*nb+2] - PC[3*nb+2];
                }
            }
            float invdeg = 1.0f / (float)L[10*vl + 9];
            float dx = mvx - sx * invdeg;
            float dy = mvy - sy * invdeg;
            float dz = mvz - sz * invdeg;
            float t = dx*dx + dy*dy + dz*dz;
            if (m > 0) t += mvx*mvx + mvy*mvy + mvz*mvz;
            lp += t * (lapc[m] / (float)NVs[m]);
        }
    }

    __shared__ float sred[12];
    __shared__ int is_last;
    for (int off = 32; off; off >>= 1) {
        ch += __shfl_down(ch, off, 64);
        ed += __shfl_down(ed, off, 64);
        lp += __shfl_down(lp, off, 64);
    }
    const int lane = tid & 63, wid = tid >> 6;
    if (lane == 0) { sred[wid] = ch; sred[4 + wid] = ed; sred[8 + wid] = lp; }
    __syncthreads();
    if (tid == 0) {
        partials[blockIdx.x * 4 + 0] = sred[0] + sred[1] + sred[2] + sred[3];
        partials[blockIdx.x * 4 + 1] = sred[4] + sred[5] + sred[6] + sred[7];
        partials[blockIdx.x * 4 + 2] = sred[8] + sred[9] + sred[10] + sred[11];
        __threadfence();
        unsigned prev = atomicAdd(counter, 1u);
        is_last = (prev == (unsigned)(gridDim.x - 1)) ? 1 : 0;
    }
    __syncthreads();

    if (is_last) {
        __threadfence();
        float c2 = 0.f, e2 = 0.f, l2 = 0.f;
        if (tid < RB) {
            c2 = partials[4*tid]; e2 = partials[4*tid+1]; l2 = partials[4*tid+2];
        }
        for (int off = 32; off; off >>= 1) {
            c2 += __shfl_down(c2, off, 64);
            e2 += __shfl_down(e2, off, 64);
            l2 += __shfl_down(l2, off, 64);
        }
        __shared__ float s2[12];
        if (lane == 0) { s2[wid] = c2; s2[4 + wid] = e2; s2[8 + wid] = l2; }
        __syncthreads();
        if (tid == 0) {
            float C = s2[0] + s2[1];       // wids 2,3 contributed zeros
            float E = s2[4] + s2[5];
            float L = s2[8] + s2[9];
            out[0] = 100.0f * C + 0.1f * E + 0.3f * L;
            out[1] = C;
            out[2] = E;
            out[3] = L;
        }
    }
}

extern "C" void kernel_launch(void* const* d_in, const int* in_sizes, int n_in,
                              void* d_out, int out_size, void* d_ws, size_t ws_size,
                              hipStream_t stream) {
    const float* gt   = (const float*)d_in[0];
    const float* pc0  = (const float*)d_in[1];
    const float* pbd0 = (const float*)d_in[2];
    const int*   ed0  = (const int*)  d_in[3];
    const int*   li0  = (const int*)  d_in[4];
    const float* pc1  = (const float*)d_in[5];
    const float* pbd1 = (const float*)d_in[6];
    const int*   ed1  = (const int*)  d_in[7];
    const int*   li1  = (const int*)  d_in[8];
    const float* pc2  = (const float*)d_in[9];
    const float* pbd2 = (const float*)d_in[10];
    const int*   ed2  = (const int*)  d_in[11];
    const int*   li2  = (const int*)  d_in[12];

    float* ws         = (float*)d_ws;
    float4* predpack  = (float4*)(ws + OFF_PREDPACK);
    float* gtmin      = ws + OFF_GTMIN;
    float* predmin    = ws + OFF_PREDMIN;
    float* partials   = ws + OFF_PARTIALS;
    unsigned* counter = (unsigned*)(ws + OFF_COUNTER);
    float* out        = (float*)d_out;

    pack_kernel<<<(93240 + 255) / 256, 256, 0, stream>>>(
        pbd0, pbd1, pbd2, predpack, gtmin, predmin, counter);

    dim3 grid(NBLK_G, NCHUNK);
    chamfer_kernel<<<grid, 256, 0, stream>>>(gt, predpack, gtmin, predmin);

    partial_kernel<<<RB, 256, 0, stream>>>(pc0, pc1, pc2, pbd0, pbd1, pbd2,
                                           ed0, ed1, ed2, li0, li1, li2,
                                           gtmin, predmin, partials, counter, out);
}